// Round 1
// baseline (249.564 us; speedup 1.0000x reference)
//
#include <hip/hip_runtime.h>
#include <math.h>

// Problem dims (fixed by setup_inputs)
#define B_ 1
#define T_ 4
#define C_ 13
#define H_ 361
#define W_ 720
constexpr int HW   = H_ * W_;        // 259920
constexpr int N4   = T_ * HW;        // 1039680  (b=1)
constexpr int W4   = W_ / 4;         // 180
constexpr int NTHR1 = T_ * H_ * W4;  // 259920
constexpr int BLK  = 256;
constexpr int GRID2 = (N4 + BLK - 1) / BLK;  // 4062

// ws layout (floats): Up[N4] Vp[N4] Ut[N4] Vt[N4] Lp[N4] Lt[N4] adx[H_] pad -> partials (double[GRID2])
constexpr size_t PART_OFF_BYTES = (size_t)(6 * N4 + 362) * 4;  // 8-byte aligned

// ---------------------------------------------------------------------------
// K1: channel-weighted reduction U = sum_c dp[c]*u[c], V likewise (both tensors),
//     plus log(sp) fields and the per-row adx table.
// ---------------------------------------------------------------------------
__global__ __launch_bounds__(BLK) void k1_reduce(
    const float* __restrict__ pu, const float* __restrict__ pv,
    const float* __restrict__ psp,
    const float* __restrict__ tu, const float* __restrict__ tv,
    const float* __restrict__ tsp,
    const float* __restrict__ lat, const float* __restrict__ lev,
    const float* __restrict__ dxp,
    float* __restrict__ ws)
{
    const int idx = blockIdx.x * BLK + threadIdx.x;

    // per-row adx (meters per dlon unit), matching JAX f32 rounding:
    // ang = (lat * f32(pi)) / 180 in f32; cos in high precision of the f32 angle;
    // m_per_lon = f32(pi*R/180) * cos (f32 mul); adx = dx * m_per_lon (f32 mul)
    if (idx < H_) {
        const float m_per_lat = (float)(M_PI * 6371000.0 / 180.0);
        float ang = (lat[idx] * (float)M_PI) / 180.0f;
        float c   = (float)cos((double)ang);
        ws[6 * N4 + idx] = dxp[0] * (m_per_lat * c);
    }
    if (idx >= NTHR1) return;

    const int t   = idx / (H_ * W4);
    const int rem = idx - t * (H_ * W4);      // h*W4 + w4
    const int base5 = t * (C_ * HW) + rem * 4;  // element offset, c-stride = HW
    const int base4 = t * HW + rem * 4;

    // dp[c]: central diff of p_levels (=lev*100), one-sided at ends. Exact in f32.
    float p[C_];
#pragma unroll
    for (int c = 0; c < C_; ++c) p[c] = lev[c] * 100.0f;
    float dp[C_];
    dp[0] = p[1] - p[0];
    dp[C_ - 1] = p[C_ - 1] - p[C_ - 2];
#pragma unroll
    for (int c = 1; c < C_ - 1; ++c) dp[c] = (p[c + 1] - p[c - 1]) * 0.5f;

    float4 sup = {0.f, 0.f, 0.f, 0.f}, svp = sup, sut = sup, svt = sup;
#pragma unroll
    for (int c = 0; c < C_; ++c) {
        const int o = base5 + c * HW;
        const float wgt = dp[c];
        float4 a = *(const float4*)(pu + o);
        float4 b = *(const float4*)(pv + o);
        float4 x = *(const float4*)(tu + o);
        float4 y = *(const float4*)(tv + o);
        sup.x = fmaf(wgt, a.x, sup.x); sup.y = fmaf(wgt, a.y, sup.y);
        sup.z = fmaf(wgt, a.z, sup.z); sup.w = fmaf(wgt, a.w, sup.w);
        svp.x = fmaf(wgt, b.x, svp.x); svp.y = fmaf(wgt, b.y, svp.y);
        svp.z = fmaf(wgt, b.z, svp.z); svp.w = fmaf(wgt, b.w, svp.w);
        sut.x = fmaf(wgt, x.x, sut.x); sut.y = fmaf(wgt, x.y, sut.y);
        sut.z = fmaf(wgt, x.z, sut.z); sut.w = fmaf(wgt, x.w, sut.w);
        svt.x = fmaf(wgt, y.x, svt.x); svt.y = fmaf(wgt, y.y, svt.y);
        svt.z = fmaf(wgt, y.z, svt.z); svt.w = fmaf(wgt, y.w, svt.w);
    }

    float4 sa = *(const float4*)(psp + base4);
    float4 sb = *(const float4*)(tsp + base4);
    float4 la = {logf(sa.x), logf(sa.y), logf(sa.z), logf(sa.w)};
    float4 lb = {logf(sb.x), logf(sb.y), logf(sb.z), logf(sb.w)};

    *(float4*)(ws + 0 * N4 + base4) = sup;
    *(float4*)(ws + 1 * N4 + base4) = svp;
    *(float4*)(ws + 2 * N4 + base4) = sut;
    *(float4*)(ws + 3 * N4 + base4) = svt;
    *(float4*)(ws + 4 * N4 + base4) = la;
    *(float4*)(ws + 5 * N4 + base4) = lb;
}

// ---------------------------------------------------------------------------
// K2: stencil residual + squared diff, per-block double partial sums
// ---------------------------------------------------------------------------
__device__ __forceinline__ float residual_at(
    const float* __restrict__ U, const float* __restrict__ V,
    const float* __restrict__ L, const float* __restrict__ sp,
    int n, int t, int h, int w, float dt, float ady, float ax)
{
    // time derivative of log sp
    float dLdt;
    if (t == 0)            dLdt = (L[n + HW] - L[n]) / dt;
    else if (t == T_ - 1)  dLdt = (L[n] - L[n - HW]) / dt;
    else                   dLdt = (L[n + HW] - L[n - HW]) / (2.0f * dt);

    // lat derivatives (L and V)
    float dLdy, dVdy;
    if (h == 0)            { dLdy = (L[n + W_] - L[n]) / ady;  dVdy = (V[n + W_] - V[n]) / ady; }
    else if (h == H_ - 1)  { dLdy = (L[n] - L[n - W_]) / ady;  dVdy = (V[n] - V[n - W_]) / ady; }
    else {
        dLdy = (L[n + W_] - L[n - W_]) / (2.0f * ady);
        dVdy = (V[n + W_] - V[n - W_]) / (2.0f * ady);
    }

    // lon derivatives (L and U); reference: numerator (halved if interior) / adx
    float dLdx, dUdx;
    if (w == 0)            { dLdx = (L[n + 1] - L[n]) / ax;  dUdx = (U[n + 1] - U[n]) / ax; }
    else if (w == W_ - 1)  { dLdx = (L[n] - L[n - 1]) / ax;  dUdx = (U[n] - U[n - 1]) / ax; }
    else {
        dLdx = ((L[n + 1] - L[n - 1]) * 0.5f) / ax;
        dUdx = ((U[n + 1] - U[n - 1]) * 0.5f) / ax;
    }

    float s = sp[n];
    float integ = (dUdx + dVdy + U[n] * dLdx + V[n] * dLdy) / s;
    return dLdt + integ;
}

__global__ __launch_bounds__(BLK) void k2_stencil(
    const float* __restrict__ psp, const float* __restrict__ tsp,
    const float* __restrict__ ws,
    const float* __restrict__ dtp, const float* __restrict__ dyp,
    double* __restrict__ part)
{
    const int n = blockIdx.x * BLK + threadIdx.x;
    double val = 0.0;
    if (n < N4) {
        const int t = n / HW;
        const int rem = n - t * HW;
        const int h = rem / W_;
        const int w = rem - h * W_;

        const float* Up = ws;
        const float* Vp = ws + 1 * N4;
        const float* Ut = ws + 2 * N4;
        const float* Vt = ws + 3 * N4;
        const float* Lp = ws + 4 * N4;
        const float* Lt = ws + 5 * N4;
        const float* adx = ws + 6 * N4;

        const float dt = dtp[0];
        const float m_per_lat = (float)(M_PI * 6371000.0 / 180.0);
        const float ady = dyp[0] * m_per_lat;
        const float ax = adx[h];

        float rm = residual_at(Up, Vp, Lp, psp, n, t, h, w, dt, ady, ax);
        float re = residual_at(Ut, Vt, Lt, tsp, n, t, h, w, dt, ady, ax);
        float d = rm - re;
        val = (double)d * (double)d;
    }

    // block reduce (4 waves of 64)
    for (int o = 32; o > 0; o >>= 1) val += __shfl_down(val, o, 64);
    __shared__ double lds[BLK / 64];
    const int lane = threadIdx.x & 63;
    const int wid  = threadIdx.x >> 6;
    if (lane == 0) lds[wid] = val;
    __syncthreads();
    if (threadIdx.x == 0) {
        double s = lds[0] + lds[1] + lds[2] + lds[3];
        part[blockIdx.x] = s;
    }
}

// ---------------------------------------------------------------------------
// K3: final reduce of GRID2 partials -> mean -> f32 out
// ---------------------------------------------------------------------------
__global__ __launch_bounds__(BLK) void k3_final(
    const double* __restrict__ part, float* __restrict__ out)
{
    double v = 0.0;
    for (int i = threadIdx.x; i < GRID2; i += BLK) v += part[i];
    for (int o = 32; o > 0; o >>= 1) v += __shfl_down(v, o, 64);
    __shared__ double lds[BLK / 64];
    const int lane = threadIdx.x & 63;
    const int wid  = threadIdx.x >> 6;
    if (lane == 0) lds[wid] = v;
    __syncthreads();
    if (threadIdx.x == 0) {
        double s = lds[0] + lds[1] + lds[2] + lds[3];
        out[0] = (float)(s / (double)N4);
    }
}

extern "C" void kernel_launch(void* const* d_in, const int* in_sizes, int n_in,
                              void* d_out, int out_size, void* d_ws, size_t ws_size,
                              hipStream_t stream)
{
    const float* pu  = (const float*)d_in[0];
    const float* pv  = (const float*)d_in[1];
    const float* psp = (const float*)d_in[2];
    const float* tu  = (const float*)d_in[3];
    const float* tv  = (const float*)d_in[4];
    const float* tsp = (const float*)d_in[5];
    const float* lat = (const float*)d_in[6];
    const float* lev = (const float*)d_in[7];
    const float* dtp = (const float*)d_in[8];
    const float* dxp = (const float*)d_in[9];
    const float* dyp = (const float*)d_in[10];

    float*  ws   = (float*)d_ws;
    double* part = (double*)((char*)d_ws + PART_OFF_BYTES);

    const int g1 = (NTHR1 + BLK - 1) / BLK;  // 1016
    hipLaunchKernelGGL(k1_reduce, dim3(g1), dim3(BLK), 0, stream,
                       pu, pv, psp, tu, tv, tsp, lat, lev, dxp, ws);
    hipLaunchKernelGGL(k2_stencil, dim3(GRID2), dim3(BLK), 0, stream,
                       psp, tsp, ws, dtp, dyp, part);
    hipLaunchKernelGGL(k3_final, dim3(1), dim3(BLK), 0, stream,
                       part, (float*)d_out);
}

// Round 3
// 243.018 us; speedup vs baseline: 1.0269x; 1.0269x over previous
//
#include <hip/hip_runtime.h>
#include <math.h>

// Problem dims (fixed by setup_inputs): b=1, t=4, c=13, h=361, w=720
#define T_ 4
#define C_ 13
#define H_ 361
#define W_ 720
constexpr int HW    = H_ * W_;        // 259920
constexpr int N4    = T_ * HW;        // 1039680
constexpr int W4    = W_ / 4;         // 180
constexpr int NTHR1 = T_ * H_ * W4;   // 259920 (threads in k1 per tensor)
constexpr int BLK   = 256;
constexpr int G1    = (NTHR1 + BLK - 1) / BLK;  // 1016
constexpr int NTHR2 = N4 / 4;         // 259920
constexpr int G2    = (NTHR2 + BLK - 1) / BLK;  // 1016

// ws layout (floats): Up[N4] Vp[N4] Ut[N4] Vt[N4] Lp[N4] Lt[N4] adx[H_] pad -> partials (double[G2])
constexpr size_t PART_OFF_BYTES = (size_t)(6 * N4 + 362) * 4;  // 8-byte aligned

__device__ __forceinline__ float4 ld4(const float* p) { return *(const float4*)p; }

// ---------------------------------------------------------------------------
// K1: U = sum_c dp[c]*u[c] for one tensor per blockIdx.y (ILP: 13 loads in
// flight per thread), plus log(sp) fields and per-row adx table.
// ---------------------------------------------------------------------------
__global__ __launch_bounds__(BLK) void k1_reduce(
    const float* __restrict__ pu, const float* __restrict__ pv,
    const float* __restrict__ psp,
    const float* __restrict__ tu, const float* __restrict__ tv,
    const float* __restrict__ tsp,
    const float* __restrict__ lat, const float* __restrict__ lev,
    const float* __restrict__ dxp,
    float* __restrict__ ws)
{
    const int tensor = blockIdx.y;       // 0:pu->Up 1:pv->Vp 2:tu->Ut 3:tv->Vt
    const int idx = blockIdx.x * BLK + threadIdx.x;

    // per-row adx table (written once, by the tensor==2 slice)
    if (tensor == 2 && idx < H_) {
        const float m_per_lat = (float)(M_PI * 6371000.0 / 180.0);
        float ang = (lat[idx] * (float)M_PI) / 180.0f;
        float c   = (float)cos((double)ang);
        ws[6 * N4 + idx] = dxp[0] * (m_per_lat * c);
    }
    if (idx >= NTHR1) return;

    const int t    = idx / (H_ * W4);
    const int rem  = idx - t * (H_ * W4);      // h*W4 + w4
    const int base5 = t * (C_ * HW) + rem * 4; // c-stride = HW
    const int base4 = t * HW + rem * 4;

    // dp[c]: central diff of p_levels (=lev*100), one-sided ends. Exact in f32.
    float dp[C_];
    {
        float p[C_];
#pragma unroll
        for (int c = 0; c < C_; ++c) p[c] = lev[c] * 100.0f;
        dp[0] = p[1] - p[0];
        dp[C_ - 1] = p[C_ - 1] - p[C_ - 2];
#pragma unroll
        for (int c = 1; c < C_ - 1; ++c) dp[c] = (p[c + 1] - p[c - 1]) * 0.5f;
    }

    const float* src = (tensor == 0) ? pu : (tensor == 1) ? pv : (tensor == 2) ? tu : tv;

    // 13 independent loads issued back-to-back, then drained by FMAs
    float4 v[C_];
#pragma unroll
    for (int c = 0; c < C_; ++c) v[c] = ld4(src + base5 + c * HW);

    float4 acc = {0.f, 0.f, 0.f, 0.f};
#pragma unroll
    for (int c = 0; c < C_; ++c) {
        acc.x = fmaf(dp[c], v[c].x, acc.x);
        acc.y = fmaf(dp[c], v[c].y, acc.y);
        acc.z = fmaf(dp[c], v[c].z, acc.z);
        acc.w = fmaf(dp[c], v[c].w, acc.w);
    }
    *(float4*)(ws + (size_t)tensor * N4 + base4) = acc;

    if (tensor == 0) {
        float4 s4 = ld4(psp + base4);
        float4 l4 = {logf(s4.x), logf(s4.y), logf(s4.z), logf(s4.w)};
        *(float4*)(ws + 4 * N4 + base4) = l4;
    } else if (tensor == 1) {
        float4 s4 = ld4(tsp + base4);
        float4 l4 = {logf(s4.x), logf(s4.y), logf(s4.z), logf(s4.w)};
        *(float4*)(ws + 5 * N4 + base4) = l4;
    }
}

// ---------------------------------------------------------------------------
// K2: vectorized stencil residual (4 outputs/thread) + double partials
// ---------------------------------------------------------------------------
__device__ __forceinline__ void resid4(
    const float* __restrict__ U, const float* __restrict__ V,
    const float* __restrict__ L, const float* __restrict__ sp,
    int n, int t, int h, int w4, float dt, float ady, float ax,
    float out[4])
{
    float4 Uc4 = ld4(U + n), Vc4 = ld4(V + n), Lc4 = ld4(L + n), S4 = ld4(sp + n);
    const int up = (h > 0)      ? n - W_ : n;
    const int dn = (h < H_ - 1) ? n + W_ : n;
    float4 Vu4 = ld4(V + up), Vd4 = ld4(V + dn);
    float4 Lu4 = ld4(L + up), Ld4 = ld4(L + dn);
    float4 Lp4 = (t > 0)      ? ld4(L + n - HW) : Lc4;
    float4 Ln4 = (t < T_ - 1) ? ld4(L + n + HW) : Lc4;
    float Ul = (w4 > 0)      ? U[n - 1] : 0.f;
    float Ur = (w4 < W4 - 1) ? U[n + 4] : 0.f;
    float Ll = (w4 > 0)      ? L[n - 1] : 0.f;
    float Lr = (w4 < W4 - 1) ? L[n + 4] : 0.f;

    const float Uc[4] = {Uc4.x, Uc4.y, Uc4.z, Uc4.w};
    const float Vc[4] = {Vc4.x, Vc4.y, Vc4.z, Vc4.w};
    const float Lc[4] = {Lc4.x, Lc4.y, Lc4.z, Lc4.w};
    const float S[4]  = {S4.x,  S4.y,  S4.z,  S4.w};
    const float Vu[4] = {Vu4.x, Vu4.y, Vu4.z, Vu4.w};
    const float Vd[4] = {Vd4.x, Vd4.y, Vd4.z, Vd4.w};
    const float Lu[4] = {Lu4.x, Lu4.y, Lu4.z, Lu4.w};
    const float Ld[4] = {Ld4.x, Ld4.y, Ld4.z, Ld4.w};
    const float Lp[4] = {Lp4.x, Lp4.y, Lp4.z, Lp4.w};
    const float Ln[4] = {Ln4.x, Ln4.y, Ln4.z, Ln4.w};

#pragma unroll
    for (int j = 0; j < 4; ++j) {
        // time derivative of log sp
        float dLdt;
        if (t == 0)           dLdt = (Ln[j] - Lc[j]) / dt;
        else if (t == T_ - 1) dLdt = (Lc[j] - Lp[j]) / dt;
        else                  dLdt = (Ln[j] - Lp[j]) / (2.0f * dt);

        // lat derivatives
        float dLdy, dVdy;
        if (h == 0)           { dLdy = (Ld[j] - Lc[j]) / ady; dVdy = (Vd[j] - Vc[j]) / ady; }
        else if (h == H_ - 1) { dLdy = (Lc[j] - Lu[j]) / ady; dVdy = (Vc[j] - Vu[j]) / ady; }
        else {
            dLdy = (Ld[j] - Lu[j]) / (2.0f * ady);
            dVdy = (Vd[j] - Vu[j]) / (2.0f * ady);
        }

        // lon derivatives
        const float uL = (j > 0) ? Uc[j - 1] : Ul;
        const float uR = (j < 3) ? Uc[j + 1] : Ur;
        const float lL = (j > 0) ? Lc[j - 1] : Ll;
        const float lR = (j < 3) ? Lc[j + 1] : Lr;
        float dUdx, dLdx;
        const bool at0 = (w4 == 0 && j == 0);
        const bool atE = (w4 == W4 - 1 && j == 3);
        if (at0)      { dUdx = (Uc[1] - Uc[0]) / ax; dLdx = (Lc[1] - Lc[0]) / ax; }
        else if (atE) { dUdx = (Uc[3] - Uc[2]) / ax; dLdx = (Lc[3] - Lc[2]) / ax; }
        else {
            dUdx = ((uR - uL) * 0.5f) / ax;
            dLdx = ((lR - lL) * 0.5f) / ax;
        }

        float integ = (dUdx + dVdy + Uc[j] * dLdx + Vc[j] * dLdy) / S[j];
        out[j] = dLdt + integ;
    }
}

__global__ __launch_bounds__(BLK) void k2_stencil(
    const float* __restrict__ psp, const float* __restrict__ tsp,
    const float* __restrict__ ws,
    const float* __restrict__ dtp, const float* __restrict__ dyp,
    double* __restrict__ part)
{
    const int idx = blockIdx.x * BLK + threadIdx.x;
    double val = 0.0;
    if (idx < NTHR2) {
        const int t   = idx / (H_ * W4);
        const int rem = idx - t * (H_ * W4);
        const int h   = rem / W4;
        const int w4  = rem - h * W4;
        const int n   = t * HW + h * W_ + w4 * 4;

        const float* adx = ws + 6 * N4;
        const float dt = dtp[0];
        const float m_per_lat = (float)(M_PI * 6371000.0 / 180.0);
        const float ady = dyp[0] * m_per_lat;
        const float ax  = adx[h];

        float rm[4], re[4];
        resid4(ws + 0 * N4, ws + 1 * N4, ws + 4 * N4, psp, n, t, h, w4, dt, ady, ax, rm);
        resid4(ws + 2 * N4, ws + 3 * N4, ws + 5 * N4, tsp, n, t, h, w4, dt, ady, ax, re);
#pragma unroll
        for (int j = 0; j < 4; ++j) {
            float d = rm[j] - re[j];
            val += (double)d * (double)d;
        }
    }

    // block reduce (4 waves of 64)
    for (int o = 32; o > 0; o >>= 1) val += __shfl_down(val, o, 64);
    __shared__ double lds[BLK / 64];
    const int lane = threadIdx.x & 63;
    const int wid  = threadIdx.x >> 6;
    if (lane == 0) lds[wid] = val;
    __syncthreads();
    if (threadIdx.x == 0) part[blockIdx.x] = lds[0] + lds[1] + lds[2] + lds[3];
}

// ---------------------------------------------------------------------------
// K3: final reduce of G2 partials -> mean -> f32 out
// ---------------------------------------------------------------------------
__global__ __launch_bounds__(BLK) void k3_final(
    const double* __restrict__ part, float* __restrict__ out)
{
    double v = 0.0;
    for (int i = threadIdx.x; i < G2; i += BLK) v += part[i];
    for (int o = 32; o > 0; o >>= 1) v += __shfl_down(v, o, 64);
    __shared__ double lds[BLK / 64];
    const int lane = threadIdx.x & 63;
    const int wid  = threadIdx.x >> 6;
    if (lane == 0) lds[wid] = v;
    __syncthreads();
    if (threadIdx.x == 0) {
        double s = lds[0] + lds[1] + lds[2] + lds[3];
        out[0] = (float)(s / (double)N4);
    }
}

extern "C" void kernel_launch(void* const* d_in, const int* in_sizes, int n_in,
                              void* d_out, int out_size, void* d_ws, size_t ws_size,
                              hipStream_t stream)
{
    const float* pu  = (const float*)d_in[0];
    const float* pv  = (const float*)d_in[1];
    const float* psp = (const float*)d_in[2];
    const float* tu  = (const float*)d_in[3];
    const float* tv  = (const float*)d_in[4];
    const float* tsp = (const float*)d_in[5];
    const float* lat = (const float*)d_in[6];
    const float* lev = (const float*)d_in[7];
    const float* dtp = (const float*)d_in[8];
    const float* dxp = (const float*)d_in[9];
    const float* dyp = (const float*)d_in[10];

    float*  ws   = (float*)d_ws;
    double* part = (double*)((char*)d_ws + PART_OFF_BYTES);

    hipLaunchKernelGGL(k1_reduce, dim3(G1, 4), dim3(BLK), 0, stream,
                       pu, pv, psp, tu, tv, tsp, lat, lev, dxp, ws);
    hipLaunchKernelGGL(k2_stencil, dim3(G2), dim3(BLK), 0, stream,
                       psp, tsp, ws, dtp, dyp, part);
    hipLaunchKernelGGL(k3_final, dim3(1), dim3(BLK), 0, stream,
                       part, (float*)d_out);
}

// Round 5
// 242.082 us; speedup vs baseline: 1.0309x; 1.0039x over previous
//
#include <hip/hip_runtime.h>
#include <math.h>

// Problem dims (fixed by setup_inputs): b=1, t=4, c=13, h=361, w=720
#define T_ 4
#define C_ 13
#define H_ 361
#define W_ 720
constexpr int HW    = H_ * W_;        // 259920
constexpr int N4    = T_ * HW;        // 1039680
constexpr int W4    = W_ / 4;         // 180
constexpr int NTHR1 = T_ * H_ * W4;   // 259920 (threads in k1 per tensor)
constexpr int BLK   = 256;
constexpr int G1    = (NTHR1 + BLK - 1) / BLK;  // 1016
constexpr int NTHR2 = N4 / 4;         // 259920
constexpr int G2    = (NTHR2 + BLK - 1) / BLK;  // 1016

// ws layout (floats): Up[N4] Vp[N4] Ut[N4] Vt[N4] Lp[N4] Lt[N4] adx[H_] pad -> partials (double[G2])
constexpr size_t PART_OFF_BYTES = (size_t)(6 * N4 + 362) * 4;  // 8-byte aligned

__device__ __forceinline__ float4 ld4(const float* p) { return *(const float4*)p; }

// ---------------------------------------------------------------------------
// K1: U = sum_c dp[c]*u[c] for one tensor per blockIdx.y. __launch_bounds__
// (256,4) gives the register allocator ~128 VGPRs so all 13 float4 loads can
// be in flight before the first waitcnt (R3 showed VGPR=32 serialized them).
// ---------------------------------------------------------------------------
__global__ __launch_bounds__(BLK, 4) void k1_reduce(
    const float* __restrict__ pu, const float* __restrict__ pv,
    const float* __restrict__ psp,
    const float* __restrict__ tu, const float* __restrict__ tv,
    const float* __restrict__ tsp,
    const float* __restrict__ lat, const float* __restrict__ lev,
    const float* __restrict__ dxp,
    float* __restrict__ ws)
{
    const int tensor = blockIdx.y;       // 0:pu->Up 1:pv->Vp 2:tu->Ut 3:tv->Vt
    const int idx = blockIdx.x * BLK + threadIdx.x;

    // per-row adx table (written once, by the tensor==2 slice)
    if (tensor == 2 && idx < H_) {
        const float m_per_lat = (float)(M_PI * 6371000.0 / 180.0);
        float ang = (lat[idx] * (float)M_PI) / 180.0f;
        float c   = (float)cos((double)ang);
        ws[6 * N4 + idx] = dxp[0] * (m_per_lat * c);
    }
    if (idx >= NTHR1) return;

    const int t    = idx / (H_ * W4);
    const int rem  = idx - t * (H_ * W4);      // h*W4 + w4
    const int base5 = t * (C_ * HW) + rem * 4; // c-stride = HW
    const int base4 = t * HW + rem * 4;

    const float* src = (tensor == 0) ? pu : (tensor == 1) ? pv : (tensor == 2) ? tu : tv;

    // 13 independent loads issued back-to-back, then drained by FMAs
    float4 v[C_];
#pragma unroll
    for (int c = 0; c < C_; ++c) v[c] = ld4(src + base5 + c * HW);

    // dp[c]: central diff of p_levels (=lev*100), one-sided ends. Exact in f32.
    float dp[C_];
    {
        float p[C_];
#pragma unroll
        for (int c = 0; c < C_; ++c) p[c] = lev[c] * 100.0f;
        dp[0] = p[1] - p[0];
        dp[C_ - 1] = p[C_ - 1] - p[C_ - 2];
#pragma unroll
        for (int c = 1; c < C_ - 1; ++c) dp[c] = (p[c + 1] - p[c - 1]) * 0.5f;
    }

    float4 acc = {0.f, 0.f, 0.f, 0.f};
#pragma unroll
    for (int c = 0; c < C_; ++c) {
        acc.x = fmaf(dp[c], v[c].x, acc.x);
        acc.y = fmaf(dp[c], v[c].y, acc.y);
        acc.z = fmaf(dp[c], v[c].z, acc.z);
        acc.w = fmaf(dp[c], v[c].w, acc.w);
    }
    *(float4*)(ws + (size_t)tensor * N4 + base4) = acc;

    if (tensor == 0) {
        float4 s4 = ld4(psp + base4);
        float4 l4 = {logf(s4.x), logf(s4.y), logf(s4.z), logf(s4.w)};
        *(float4*)(ws + 4 * N4 + base4) = l4;
    } else if (tensor == 1) {
        float4 s4 = ld4(tsp + base4);
        float4 l4 = {logf(s4.x), logf(s4.y), logf(s4.z), logf(s4.w)};
        *(float4*)(ws + 5 * N4 + base4) = l4;
    }
}

// ---------------------------------------------------------------------------
// K2: vectorized stencil residual (4 outputs/thread) + double partials
// ---------------------------------------------------------------------------
__device__ __forceinline__ void resid4(
    const float* __restrict__ U, const float* __restrict__ V,
    const float* __restrict__ L, const float* __restrict__ sp,
    int n, int t, int h, int w4, float dt, float ady, float ax,
    float out[4])
{
    float4 Uc4 = ld4(U + n), Vc4 = ld4(V + n), Lc4 = ld4(L + n), S4 = ld4(sp + n);
    const int up = (h > 0)      ? n - W_ : n;
    const int dn = (h < H_ - 1) ? n + W_ : n;
    float4 Vu4 = ld4(V + up), Vd4 = ld4(V + dn);
    float4 Lu4 = ld4(L + up), Ld4 = ld4(L + dn);
    float4 Lp4 = (t > 0)      ? ld4(L + n - HW) : Lc4;
    float4 Ln4 = (t < T_ - 1) ? ld4(L + n + HW) : Lc4;
    float Ul = (w4 > 0)      ? U[n - 1] : 0.f;
    float Ur = (w4 < W4 - 1) ? U[n + 4] : 0.f;
    float Ll = (w4 > 0)      ? L[n - 1] : 0.f;
    float Lr = (w4 < W4 - 1) ? L[n + 4] : 0.f;

    const float Uc[4] = {Uc4.x, Uc4.y, Uc4.z, Uc4.w};
    const float Vc[4] = {Vc4.x, Vc4.y, Vc4.z, Vc4.w};
    const float Lc[4] = {Lc4.x, Lc4.y, Lc4.z, Lc4.w};
    const float S[4]  = {S4.x,  S4.y,  S4.z,  S4.w};
    const float Vu[4] = {Vu4.x, Vu4.y, Vu4.z, Vu4.w};
    const float Vd[4] = {Vd4.x, Vd4.y, Vd4.z, Vd4.w};
    const float Lu[4] = {Lu4.x, Lu4.y, Lu4.z, Lu4.w};
    const float Ld[4] = {Ld4.x, Ld4.y, Ld4.z, Ld4.w};
    const float Lp[4] = {Lp4.x, Lp4.y, Lp4.z, Lp4.w};
    const float Ln[4] = {Ln4.x, Ln4.y, Ln4.z, Ln4.w};

#pragma unroll
    for (int j = 0; j < 4; ++j) {
        // time derivative of log sp
        float dLdt;
        if (t == 0)           dLdt = (Ln[j] - Lc[j]) / dt;
        else if (t == T_ - 1) dLdt = (Lc[j] - Lp[j]) / dt;
        else                  dLdt = (Ln[j] - Lp[j]) / (2.0f * dt);

        // lat derivatives
        float dLdy, dVdy;
        if (h == 0)           { dLdy = (Ld[j] - Lc[j]) / ady; dVdy = (Vd[j] - Vc[j]) / ady; }
        else if (h == H_ - 1) { dLdy = (Lc[j] - Lu[j]) / ady; dVdy = (Vc[j] - Vu[j]) / ady; }
        else {
            dLdy = (Ld[j] - Lu[j]) / (2.0f * ady);
            dVdy = (Vd[j] - Vu[j]) / (2.0f * ady);
        }

        // lon derivatives
        const float uL = (j > 0) ? Uc[j - 1] : Ul;
        const float uR = (j < 3) ? Uc[j + 1] : Ur;
        const float lL = (j > 0) ? Lc[j - 1] : Ll;
        const float lR = (j < 3) ? Lc[j + 1] : Lr;
        float dUdx, dLdx;
        const bool at0 = (w4 == 0 && j == 0);
        const bool atE = (w4 == W4 - 1 && j == 3);
        if (at0)      { dUdx = (Uc[1] - Uc[0]) / ax; dLdx = (Lc[1] - Lc[0]) / ax; }
        else if (atE) { dUdx = (Uc[3] - Uc[2]) / ax; dLdx = (Lc[3] - Lc[2]) / ax; }
        else {
            dUdx = ((uR - uL) * 0.5f) / ax;
            dLdx = ((lR - lL) * 0.5f) / ax;
        }

        float integ = (dUdx + dVdy + Uc[j] * dLdx + Vc[j] * dLdy) / S[j];
        out[j] = dLdt + integ;
    }
}

__global__ __launch_bounds__(BLK, 4) void k2_stencil(
    const float* __restrict__ psp, const float* __restrict__ tsp,
    const float* __restrict__ ws,
    const float* __restrict__ dtp, const float* __restrict__ dyp,
    double* __restrict__ part)
{
    const int idx = blockIdx.x * BLK + threadIdx.x;
    double val = 0.0;
    if (idx < NTHR2) {
        const int t   = idx / (H_ * W4);
        const int rem = idx - t * (H_ * W4);
        const int h   = rem / W4;
        const int w4  = rem - h * W4;
        const int n   = t * HW + h * W_ + w4 * 4;

        const float* adx = ws + 6 * N4;
        const float dt = dtp[0];
        const float m_per_lat = (float)(M_PI * 6371000.0 / 180.0);
        const float ady = dyp[0] * m_per_lat;
        const float ax  = adx[h];

        float rm[4], re[4];
        resid4(ws + 0 * N4, ws + 1 * N4, ws + 4 * N4, psp, n, t, h, w4, dt, ady, ax, rm);
        resid4(ws + 2 * N4, ws + 3 * N4, ws + 5 * N4, tsp, n, t, h, w4, dt, ady, ax, re);
#pragma unroll
        for (int j = 0; j < 4; ++j) {
            float d = rm[j] - re[j];
            val += (double)d * (double)d;
        }
    }

    // block reduce (4 waves of 64)
    for (int o = 32; o > 0; o >>= 1) val += __shfl_down(val, o, 64);
    __shared__ double lds[BLK / 64];
    const int lane = threadIdx.x & 63;
    const int wid  = threadIdx.x >> 6;
    if (lane == 0) lds[wid] = val;
    __syncthreads();
    if (threadIdx.x == 0) part[blockIdx.x] = lds[0] + lds[1] + lds[2] + lds[3];
}

// ---------------------------------------------------------------------------
// K3: final reduce of G2 partials -> mean -> f32 out
// ---------------------------------------------------------------------------
__global__ __launch_bounds__(BLK) void k3_final(
    const double* __restrict__ part, float* __restrict__ out)
{
    double v = 0.0;
    for (int i = threadIdx.x; i < G2; i += BLK) v += part[i];
    for (int o = 32; o > 0; o >>= 1) v += __shfl_down(v, o, 64);
    __shared__ double lds[BLK / 64];
    const int lane = threadIdx.x & 63;
    const int wid  = threadIdx.x >> 6;
    if (lane == 0) lds[wid] = v;
    __syncthreads();
    if (threadIdx.x == 0) {
        double s = lds[0] + lds[1] + lds[2] + lds[3];
        out[0] = (float)(s / (double)N4);
    }
}

extern "C" void kernel_launch(void* const* d_in, const int* in_sizes, int n_in,
                              void* d_out, int out_size, void* d_ws, size_t ws_size,
                              hipStream_t stream)
{
    const float* pu  = (const float*)d_in[0];
    const float* pv  = (const float*)d_in[1];
    const float* psp = (const float*)d_in[2];
    const float* tu  = (const float*)d_in[3];
    const float* tv  = (const float*)d_in[4];
    const float* tsp = (const float*)d_in[5];
    const float* lat = (const float*)d_in[6];
    const float* lev = (const float*)d_in[7];
    const float* dtp = (const float*)d_in[8];
    const float* dxp = (const float*)d_in[9];
    const float* dyp = (const float*)d_in[10];

    float*  ws   = (float*)d_ws;
    double* part = (double*)((char*)d_ws + PART_OFF_BYTES);

    hipLaunchKernelGGL(k1_reduce, dim3(G1, 4), dim3(BLK), 0, stream,
                       pu, pv, psp, tu, tv, tsp, lat, lev, dxp, ws);
    hipLaunchKernelGGL(k2_stencil, dim3(G2), dim3(BLK), 0, stream,
                       psp, tsp, ws, dtp, dyp, part);
    hipLaunchKernelGGL(k3_final, dim3(1), dim3(BLK), 0, stream,
                       part, (float*)d_out);
}